// Round 1
// baseline (770.218 us; speedup 1.0000x reference)
//
#include <hip/hip_runtime.h>

// GCN 2-layer: out = gcn(relu(gcn(x, W1, b1)), W2, b2)
// N=100000 nodes, E=1600000 edges (+N self-loops), D 128->128->64, fp32.
// Plan: build CSR by dst once (count + scan + fill), dinv = rsqrt(deg+1),
// per-layer: dense GEMM (h = x@W) then per-node gather-aggregate.

#define NN 100000
#define EE 1600000

// ---------- edge dtype detection (int32 vs int64) ----------
// If int64 (little-endian, values in [0,N)), every odd 32-bit word is 0.
__global__ void detect_kernel(const void* ei, int* flag) {
    __shared__ int any_nz;
    if (threadIdx.x == 0) any_nz = 0;
    __syncthreads();
    unsigned v = ((const unsigned*)ei)[2 * (size_t)threadIdx.x + 1];
    if (v != 0) atomicAdd(&any_nz, 1);
    __syncthreads();
    if (threadIdx.x == 0) *flag = (any_nz == 0) ? 1 : 0;  // 1 => int64
}

__device__ __forceinline__ int load_idx(const void* p, long long i, int is64) {
    if (is64) return (int)((const long long*)p)[i];
    return ((const int*)p)[i];
}

// ---------- CSR build ----------
__global__ void count_deg(const void* ei, const int* flag, int* cnt) {
    int i = blockIdx.x * 256 + threadIdx.x;
    if (i >= EE) return;
    int is64 = *flag;
    int d = load_idx(ei, (long long)EE + i, is64);  // dst row
    atomicAdd(&cnt[d], 1);
}

__global__ void scan_kernel(const int* __restrict__ cnt, int* __restrict__ row_start) {
    __shared__ int sums[1024];
    int tid = threadIdx.x;
    const int chunk = (NN + 1023) / 1024;  // 98
    int begin = tid * chunk;
    int end = min(begin + chunk, NN);
    int s = 0;
    for (int i = begin; i < end; i++) s += cnt[i];
    sums[tid] = s;
    __syncthreads();
    for (int off = 1; off < 1024; off <<= 1) {
        int v = 0;
        if (tid >= off) v = sums[tid - off];
        __syncthreads();
        if (tid >= off) sums[tid] += v;
        __syncthreads();
    }
    int excl = (tid == 0) ? 0 : sums[tid - 1];
    for (int i = begin; i < end; i++) { row_start[i] = excl; excl += cnt[i]; }
    if (tid == 1023) row_start[NN] = excl;
}

__global__ void dinv_kernel(const int* __restrict__ cnt, float* __restrict__ dinv) {
    int i = blockIdx.x * 256 + threadIdx.x;
    if (i < NN) dinv[i] = rsqrtf((float)(cnt[i] + 1));  // +1 = self loop
}

__global__ void fill_csr(const void* ei, const int* flag, const int* __restrict__ row_start,
                         int* __restrict__ fillc, int* __restrict__ col) {
    int i = blockIdx.x * 256 + threadIdx.x;
    if (i >= EE) return;
    int is64 = *flag;
    int s = load_idx(ei, i, is64);                  // src row
    int d = load_idx(ei, (long long)EE + i, is64);  // dst row
    int slot = row_start[d] + atomicAdd(&fillc[d], 1);
    col[slot] = s;
}

// ---------- GEMM: H[N][M] = X[N][128] @ W[128][M], M in {128, 64} ----------
// 64x64 C-tile per block, 256 threads, TM=TN=4, full K=128 staged in LDS.
template <int M>
__global__ __launch_bounds__(256) void gemm_kernel(const float* __restrict__ X,
                                                   const float* __restrict__ W,
                                                   float* __restrict__ H) {
    __shared__ float xs[128][68];  // transposed x tile: xs[k][row], pad 68 keeps 16B align
    __shared__ float ws[128][64];  // W tile: ws[k][col]
    const int tid = threadIdx.x;
    const int r0 = blockIdx.x * 64;
    const int c0 = blockIdx.y * 64;

    // load x tile (64 rows x 128 k) as float4, store transposed
    #pragma unroll
    for (int it = 0; it < 8; ++it) {
        int idx = tid + it * 256;  // 0..2047 float4s
        int r = idx >> 5;          // row 0..63
        int kq = idx & 31;         // float4 index along k
        float4 v = make_float4(0.f, 0.f, 0.f, 0.f);
        if (r0 + r < NN) v = *(const float4*)(X + (size_t)(r0 + r) * 128 + kq * 4);
        xs[kq * 4 + 0][r] = v.x;
        xs[kq * 4 + 1][r] = v.y;
        xs[kq * 4 + 2][r] = v.z;
        xs[kq * 4 + 3][r] = v.w;
    }
    // load W tile (128 x 64)
    #pragma unroll
    for (int it = 0; it < 8; ++it) {
        int idx = tid + it * 256;  // 0..2047 float4s
        int k = idx >> 4;
        int cq = idx & 15;
        *(float4*)&ws[k][cq * 4] = *(const float4*)(W + (size_t)k * M + c0 + cq * 4);
    }
    __syncthreads();

    const int ty = tid >> 4, tx = tid & 15;
    float acc[4][4] = {{0.f}};
    #pragma unroll 8
    for (int k = 0; k < 128; k++) {
        float4 av = *(const float4*)&xs[k][ty * 4];
        float4 bv = *(const float4*)&ws[k][tx * 4];
        float a[4] = {av.x, av.y, av.z, av.w};
        float b[4] = {bv.x, bv.y, bv.z, bv.w};
        #pragma unroll
        for (int i = 0; i < 4; i++)
            #pragma unroll
            for (int j = 0; j < 4; j++) acc[i][j] += a[i] * b[j];
    }

    #pragma unroll
    for (int i = 0; i < 4; i++) {
        int r = r0 + ty * 4 + i;
        if (r < NN) {
            float4 o = make_float4(acc[i][0], acc[i][1], acc[i][2], acc[i][3]);
            *(float4*)(H + (size_t)r * M + c0 + tx * 4) = o;
        }
    }
}

// ---------- aggregation: out[v] = dinv[v]*(h[v]*dinv[v] + sum_in h[u]*dinv[u]) + b ----------
// one wave per node; D=128 -> float2/lane, D=64 -> float/lane
template <int D, bool RELU>
__global__ __launch_bounds__(256) void agg_kernel(const float* __restrict__ h,
                                                  const int* __restrict__ row_start,
                                                  const int* __restrict__ col,
                                                  const float* __restrict__ dinv,
                                                  const float* __restrict__ bias,
                                                  float* __restrict__ out) {
    int node = (blockIdx.x * 256 + threadIdx.x) >> 6;
    int lane = threadIdx.x & 63;
    if (node >= NN) return;
    float di = dinv[node];
    int s = row_start[node], e = row_start[node + 1];
    if (D == 128) {
        float2 acc = ((const float2*)(h + (size_t)node * 128))[lane];
        acc.x *= di; acc.y *= di;  // self loop: h[v]*dinv[v]
        for (int j = s; j < e; j++) {
            int c = col[j];
            float w = dinv[c];
            float2 v = ((const float2*)(h + (size_t)c * 128))[lane];
            acc.x += v.x * w;
            acc.y += v.y * w;
        }
        float2 bv = ((const float2*)bias)[lane];
        float ox = acc.x * di + bv.x;
        float oy = acc.y * di + bv.y;
        if (RELU) { ox = fmaxf(ox, 0.f); oy = fmaxf(oy, 0.f); }
        ((float2*)(out + (size_t)node * 128))[lane] = make_float2(ox, oy);
    } else {
        float acc = h[(size_t)node * 64 + lane] * di;
        for (int j = s; j < e; j++) {
            int c = col[j];
            acc += h[(size_t)c * 64 + lane] * dinv[c];
        }
        float o = acc * di + bias[lane];
        if (RELU) o = fmaxf(o, 0.f);
        out[(size_t)node * 64 + lane] = o;
    }
}

extern "C" void kernel_launch(void* const* d_in, const int* in_sizes, int n_in,
                              void* d_out, int out_size, void* d_ws, size_t ws_size,
                              hipStream_t stream) {
    const float* x  = (const float*)d_in[0];
    const void*  ei = d_in[1];
    const float* W1 = (const float*)d_in[2];
    const float* b1 = (const float*)d_in[3];
    const float* W2 = (const float*)d_in[4];
    const float* b2 = (const float*)d_in[5];
    float* out = (float*)d_out;

    char* wsp = (char*)d_ws;
    size_t off = 0;
    auto alloc = [&](size_t bytes) {
        void* p = wsp + off;
        off += (bytes + 255) & ~(size_t)255;
        return p;
    };
    float* bufA      = (float*)alloc((size_t)NN * 128 * 4);  // h pre-agg (reused layer2)
    float* bufB      = (float*)alloc((size_t)NN * 128 * 4);  // layer1 output
    int*   col       = (int*)alloc((size_t)EE * 4);
    int*   row_start = (int*)alloc((size_t)(NN + 1) * 4);
    int*   cnt       = (int*)alloc((size_t)NN * 4);
    int*   fillc     = (int*)alloc((size_t)NN * 4);
    float* dinv      = (float*)alloc((size_t)NN * 4);
    int*   flag      = (int*)alloc(256);
    (void)ws_size; (void)in_sizes; (void)n_in; (void)out_size;

    hipMemsetAsync(cnt, 0, (size_t)NN * 4, stream);
    hipMemsetAsync(fillc, 0, (size_t)NN * 4, stream);

    detect_kernel<<<1, 512, 0, stream>>>(ei, flag);
    count_deg<<<(EE + 255) / 256, 256, 0, stream>>>(ei, flag, cnt);
    scan_kernel<<<1, 1024, 0, stream>>>(cnt, row_start);
    dinv_kernel<<<(NN + 255) / 256, 256, 0, stream>>>(cnt, dinv);
    fill_csr<<<(EE + 255) / 256, 256, 0, stream>>>(ei, flag, row_start, fillc, col);

    dim3 g1((NN + 63) / 64, 2);
    gemm_kernel<128><<<g1, 256, 0, stream>>>(x, W1, bufA);
    agg_kernel<128, true><<<(NN * 64 + 255) / 256, 256, 0, stream>>>(bufA, row_start, col, dinv, b1, bufB);
    dim3 g2((NN + 63) / 64, 1);
    gemm_kernel<64><<<g2, 256, 0, stream>>>(bufB, W2, bufA);
    agg_kernel<64, false><<<(NN * 64 + 255) / 256, 256, 0, stream>>>(bufA, row_start, col, dinv, b2, out);
}

// Round 2
// 625.012 us; speedup vs baseline: 1.2323x; 1.2323x over previous
//
#include <hip/hip_runtime.h>

// GCN 2-layer on MI355X. CSR-by-dst gather aggregation (no float atomics),
// fp16 h storage (halves gather bytes), f16-MFMA GEMM with hi/lo split
// (xh@Wh + xl@Wh + xh@Wl, fp32 accum -> better than fp32 vector GEMM).

#define NN 100000
#define EE 1600000

typedef _Float16 f16;
typedef _Float16 f16x8 __attribute__((ext_vector_type(8)));
typedef _Float16 f16x2 __attribute__((ext_vector_type(2)));
typedef float f32x4 __attribute__((ext_vector_type(4)));

// ---------- edge dtype detection (int32 vs int64) ----------
__global__ void detect_kernel(const void* ei, int* flag) {
    __shared__ int any_nz;
    if (threadIdx.x == 0) any_nz = 0;
    __syncthreads();
    unsigned v = ((const unsigned*)ei)[2 * (size_t)threadIdx.x + 1];
    if (v != 0) atomicAdd(&any_nz, 1);
    __syncthreads();
    if (threadIdx.x == 0) *flag = (any_nz == 0) ? 1 : 0;  // 1 => int64
}

__device__ __forceinline__ int load_idx(const void* p, long long i, int is64) {
    if (is64) return (int)((const long long*)p)[i];
    return ((const int*)p)[i];
}

// ---------- CSR build ----------
__global__ void count_deg(const void* ei, const int* flag, int* cnt) {
    int i = blockIdx.x * 256 + threadIdx.x;
    if (i >= EE) return;
    int is64 = *flag;
    int d = load_idx(ei, (long long)EE + i, is64);
    atomicAdd(&cnt[d], 1);
}

__global__ void scan_kernel(const int* __restrict__ cnt, int* __restrict__ row_start) {
    __shared__ int sums[1024];
    int tid = threadIdx.x;
    const int chunk = (NN + 1023) / 1024;
    int begin = tid * chunk;
    int end = min(begin + chunk, NN);
    int s = 0;
    for (int i = begin; i < end; i++) s += cnt[i];
    sums[tid] = s;
    __syncthreads();
    for (int off = 1; off < 1024; off <<= 1) {
        int v = 0;
        if (tid >= off) v = sums[tid - off];
        __syncthreads();
        if (tid >= off) sums[tid] += v;
        __syncthreads();
    }
    int excl = (tid == 0) ? 0 : sums[tid - 1];
    for (int i = begin; i < end; i++) { row_start[i] = excl; excl += cnt[i]; }
    if (tid == 1023) row_start[NN] = excl;
}

__global__ void dinv_kernel(const int* __restrict__ cnt, float* __restrict__ dinv) {
    int i = blockIdx.x * 256 + threadIdx.x;
    if (i < NN) dinv[i] = rsqrtf((float)(cnt[i] + 1));
}

__global__ void fill_csr(const void* ei, const int* flag, const int* __restrict__ row_start,
                         int* __restrict__ fillc, int* __restrict__ col) {
    int i = blockIdx.x * 256 + threadIdx.x;
    if (i >= EE) return;
    int is64 = *flag;
    int s = load_idx(ei, i, is64);
    int d = load_idx(ei, (long long)EE + i, is64);
    int slot = row_start[d] + atomicAdd(&fillc[d], 1);
    col[slot] = s;
}

// ---------- weight prep: split fp32 W[K][M] into f16 hi/lo, transposed [n][k], XOR-swizzled ----------
__global__ void prep_split(const float* __restrict__ W1, const float* __restrict__ W2,
                           f16* __restrict__ W1h, f16* __restrict__ W1l,
                           f16* __restrict__ W2h, f16* __restrict__ W2l) {
    int t = blockIdx.x * 256 + threadIdx.x;
    if (t < 128 * 128) {
        int k = t >> 7, n = t & 127;
        float v = W1[t];
        f16 h = (f16)v;
        f16 l = (f16)(v - (float)h);
        int idx = n * 128 + (k ^ ((n & 7) << 3));
        W1h[idx] = h; W1l[idx] = l;
    } else if (t < 128 * 128 + 128 * 64) {
        int u = t - 128 * 128;
        int k = u >> 6, n = u & 63;
        float v = W2[u];
        f16 h = (f16)v;
        f16 l = (f16)(v - (float)h);
        int idx = n * 128 + (k ^ ((n & 7) << 3));
        W2h[idx] = h; W2l[idx] = l;
    }
}

// ---------- GEMM via f16 MFMA, hi/lo split. H[N][M] = X[N][128] @ W[128][M] ----------
// Block: 256 thr = 4 waves, 16 rows/wave -> 64 rows/block. Whole split-W in LDS.
// SPLIT_A=1: X is fp32, split into ah+al (3 mfma). SPLIT_A=0: X already f16 (2 mfma).
template <int M, int SPLIT_A>
__global__ __launch_bounds__(256) void gemm_mfma(const void* __restrict__ Xv,
                                                 const f16* __restrict__ Wh,
                                                 const f16* __restrict__ Wl,
                                                 f16* __restrict__ H) {
    __shared__ f16 wsh[M * 128];
    __shared__ f16 wsl[M * 128];
    const int tid = threadIdx.x;
    for (int c = tid; c < M * 16; c += 256) {
        *(float4*)&wsh[c * 8] = ((const float4*)Wh)[c];
        *(float4*)&wsl[c * 8] = ((const float4*)Wl)[c];
    }
    __syncthreads();

    const int lane = tid & 63;
    const int wv = tid >> 6;
    const int m0 = lane & 15;   // A row within tile / B col within n-tile
    const int kg = lane >> 4;   // k-group 0..3
    int row = blockIdx.x * 64 + wv * 16 + m0;
    if (row >= NN) row = NN - 1;  // clamp; stores are guarded

    constexpr int NT = M / 16;
    f32x4 acc[NT];
    #pragma unroll
    for (int i = 0; i < NT; i++) acc[i] = (f32x4){0.f, 0.f, 0.f, 0.f};

    #pragma unroll
    for (int kt = 0; kt < 4; ++kt) {
        int k0 = kt * 32 + kg * 8;
        f16x8 ah, al;
        if (SPLIT_A) {
            const float* xr = (const float*)Xv + (size_t)row * 128 + k0;
            float xv[8];
            *(float4*)&xv[0] = *(const float4*)xr;
            *(float4*)&xv[4] = *(const float4*)(xr + 4);
            #pragma unroll
            for (int r = 0; r < 8; r++) {
                ah[r] = (f16)xv[r];
                al[r] = (f16)(xv[r] - (float)ah[r]);
            }
        } else {
            ah = *(const f16x8*)((const f16*)Xv + (size_t)row * 128 + k0);
        }
        #pragma unroll
        for (int nt = 0; nt < NT; ++nt) {
            int n = nt * 16 + m0;
            int sch = (kt * 4 + kg) ^ (n & 7);
            int off = n * 128 + sch * 8;
            f16x8 bh = *(const f16x8*)&wsh[off];
            f16x8 bl = *(const f16x8*)&wsl[off];
            acc[nt] = __builtin_amdgcn_mfma_f32_16x16x32_f16(ah, bh, acc[nt], 0, 0, 0);
            if (SPLIT_A)
                acc[nt] = __builtin_amdgcn_mfma_f32_16x16x32_f16(al, bh, acc[nt], 0, 0, 0);
            acc[nt] = __builtin_amdgcn_mfma_f32_16x16x32_f16(ah, bl, acc[nt], 0, 0, 0);
        }
    }

    // C/D layout (m89-verified): col = lane&15, row = (lane>>4)*4 + reg
    int r0 = blockIdx.x * 64 + wv * 16 + kg * 4;
    #pragma unroll
    for (int nt = 0; nt < NT; ++nt) {
        int cidx = nt * 16 + m0;
        #pragma unroll
        for (int i = 0; i < 4; i++) {
            int r = r0 + i;
            if (r < NN) H[(size_t)r * M + cidx] = (f16)acc[nt][i];
        }
    }
}

// ---------- aggregation D=128: fp16 in, fp16 out (relu). One wave per node. ----------
__global__ __launch_bounds__(256) void agg128(const f16* __restrict__ h,
                                              const int* __restrict__ rs,
                                              const int* __restrict__ col,
                                              const float* __restrict__ dinv,
                                              const float* __restrict__ bias,
                                              f16* __restrict__ out) {
    int node = (blockIdx.x * 256 + threadIdx.x) >> 6;
    int lane = threadIdx.x & 63;
    if (node >= NN) return;
    float di = dinv[node];
    f16x2 sv = ((const f16x2*)(h + (size_t)node * 128))[lane];
    float ax = (float)sv[0] * di, ay = (float)sv[1] * di;
    int s = rs[node], e = rs[node + 1];
    for (int j = s; j < e; ++j) {
        int c = col[j];
        float w = dinv[c];
        f16x2 v = ((const f16x2*)(h + (size_t)c * 128))[lane];
        ax += (float)v[0] * w;
        ay += (float)v[1] * w;
    }
    float2 bv = ((const float2*)bias)[lane];
    float ox = fmaxf(ax * di + bv.x, 0.f);
    float oy = fmaxf(ay * di + bv.y, 0.f);
    f16x2 o;
    o[0] = (f16)ox; o[1] = (f16)oy;
    ((f16x2*)(out + (size_t)node * 128))[lane] = o;
}

// ---------- aggregation D=64: fp16 in, fp32 out. 32 threads per node. ----------
__global__ __launch_bounds__(256) void agg64(const f16* __restrict__ h,
                                             const int* __restrict__ rs,
                                             const int* __restrict__ col,
                                             const float* __restrict__ dinv,
                                             const float* __restrict__ bias,
                                             float* __restrict__ out) {
    int node = (blockIdx.x * 256 + threadIdx.x) >> 5;
    int lane = threadIdx.x & 31;
    if (node >= NN) return;
    float di = dinv[node];
    f16x2 sv = ((const f16x2*)(h + (size_t)node * 64))[lane];
    float ax = (float)sv[0] * di, ay = (float)sv[1] * di;
    int s = rs[node], e = rs[node + 1];
    for (int j = s; j < e; ++j) {
        int c = col[j];
        float w = dinv[c];
        f16x2 v = ((const f16x2*)(h + (size_t)c * 64))[lane];
        ax += (float)v[0] * w;
        ay += (float)v[1] * w;
    }
    float2 bv = ((const float2*)bias)[lane];
    float2 o = make_float2(ax * di + bv.x, ay * di + bv.y);
    ((float2*)(out + (size_t)node * 64))[lane] = o;
}

extern "C" void kernel_launch(void* const* d_in, const int* in_sizes, int n_in,
                              void* d_out, int out_size, void* d_ws, size_t ws_size,
                              hipStream_t stream) {
    const float* x  = (const float*)d_in[0];
    const void*  ei = d_in[1];
    const float* W1 = (const float*)d_in[2];
    const float* b1 = (const float*)d_in[3];
    const float* W2 = (const float*)d_in[4];
    const float* b2 = (const float*)d_in[5];
    float* out = (float*)d_out;

    char* wsp = (char*)d_ws;
    size_t off = 0;
    auto alloc = [&](size_t bytes) {
        void* p = wsp + off;
        off += (bytes + 255) & ~(size_t)255;
        return p;
    };
    f16*   h1        = (f16*)alloc((size_t)NN * 128 * 2);  // gemm1 out
    f16*   a1        = (f16*)alloc((size_t)NN * 128 * 2);  // agg1 out (layer-2 input)
    f16*   h2        = (f16*)alloc((size_t)NN * 64 * 2);   // gemm2 out
    int*   col       = (int*)alloc((size_t)EE * 4);
    int*   row_start = (int*)alloc((size_t)(NN + 1) * 4);
    int*   cnt       = (int*)alloc((size_t)NN * 4);
    int*   fillc     = (int*)alloc((size_t)NN * 4);
    float* dinv      = (float*)alloc((size_t)NN * 4);
    int*   flag      = (int*)alloc(256);
    f16*   W1h       = (f16*)alloc(128 * 128 * 2);
    f16*   W1l       = (f16*)alloc(128 * 128 * 2);
    f16*   W2h       = (f16*)alloc(64 * 128 * 2);
    f16*   W2l       = (f16*)alloc(64 * 128 * 2);
    (void)ws_size; (void)in_sizes; (void)n_in; (void)out_size;

    hipMemsetAsync(cnt, 0, (size_t)NN * 4, stream);
    hipMemsetAsync(fillc, 0, (size_t)NN * 4, stream);

    detect_kernel<<<1, 512, 0, stream>>>(ei, flag);
    prep_split<<<96, 256, 0, stream>>>(W1, W2, W1h, W1l, W2h, W2l);
    count_deg<<<(EE + 255) / 256, 256, 0, stream>>>(ei, flag, cnt);
    scan_kernel<<<1, 1024, 0, stream>>>(cnt, row_start);
    dinv_kernel<<<(NN + 255) / 256, 256, 0, stream>>>(cnt, dinv);
    fill_csr<<<(EE + 255) / 256, 256, 0, stream>>>(ei, flag, row_start, fillc, col);

    gemm_mfma<128, 1><<<(NN + 63) / 64, 256, 0, stream>>>(x, W1h, W1l, h1);
    agg128<<<(NN * 64) / 256, 256, 0, stream>>>(h1, row_start, col, dinv, b1, a1);
    gemm_mfma<64, 0><<<(NN + 63) / 64, 256, 0, stream>>>(a1, W2h, W2l, h2);
    agg64<<<(NN * 32) / 256, 256, 0, stream>>>(h2, row_start, col, dinv, b2, out);
}

// Round 3
// 462.262 us; speedup vs baseline: 1.6662x; 1.3521x over previous
//
#include <hip/hip_runtime.h>

// GCN 2-layer on MI355X. CSR-by-dst gather aggregation (no float atomics),
// fp16 h storage (halves gather bytes), f16-MFMA GEMM with hi/lo split
// (xh@Wh + xl@Wh + xh@Wl, fp32 accum -> better than fp32 vector GEMM).
// R2 fix: single-block scan (159us, serialized on 1 CU) -> 2-kernel
// multi-block scan (~6us), dinv fused into scan phase 1.

#define NN 100000
#define EE 1600000
#define SCAN_NBLK ((NN + 1023) / 1024)  // 98

typedef _Float16 f16;
typedef _Float16 f16x8 __attribute__((ext_vector_type(8)));
typedef _Float16 f16x2 __attribute__((ext_vector_type(2)));
typedef float f32x4 __attribute__((ext_vector_type(4)));

// ---------- edge dtype detection (int32 vs int64) ----------
__global__ void detect_kernel(const void* ei, int* flag) {
    __shared__ int any_nz;
    if (threadIdx.x == 0) any_nz = 0;
    __syncthreads();
    unsigned v = ((const unsigned*)ei)[2 * (size_t)threadIdx.x + 1];
    if (v != 0) atomicAdd(&any_nz, 1);
    __syncthreads();
    if (threadIdx.x == 0) *flag = (any_nz == 0) ? 1 : 0;  // 1 => int64
}

__device__ __forceinline__ int load_idx(const void* p, long long i, int is64) {
    if (is64) return (int)((const long long*)p)[i];
    return ((const int*)p)[i];
}

// ---------- CSR build ----------
__global__ void count_deg(const void* ei, const int* flag, int* cnt) {
    int i = blockIdx.x * 256 + threadIdx.x;
    if (i >= EE) return;
    int is64 = *flag;
    int d = load_idx(ei, (long long)EE + i, is64);
    atomicAdd(&cnt[d], 1);
}

// multi-block exclusive scan, phase 1: per-block Hillis-Steele; also emits dinv
__global__ __launch_bounds__(1024) void scan1(const int* __restrict__ cnt,
                                              int* __restrict__ rs,
                                              int* __restrict__ bsum,
                                              float* __restrict__ dinv) {
    __shared__ int tmp[1024];
    int tid = threadIdx.x;
    int gid = blockIdx.x * 1024 + tid;
    int v = (gid < NN) ? cnt[gid] : 0;
    if (gid < NN) dinv[gid] = rsqrtf((float)(v + 1));  // +1 = self loop
    tmp[tid] = v;
    __syncthreads();
    #pragma unroll
    for (int off = 1; off < 1024; off <<= 1) {
        int t = (tid >= off) ? tmp[tid - off] : 0;
        __syncthreads();
        if (tid >= off) tmp[tid] += t;
        __syncthreads();
    }
    if (gid <= NN) rs[gid] = tmp[tid] - v;  // exclusive
    if (tid == 1023) bsum[blockIdx.x] = tmp[1023];
}

// phase 2: add block-prefix base (computed redundantly; 98 uniform loads)
__global__ __launch_bounds__(1024) void scan2(int* __restrict__ rs,
                                              const int* __restrict__ bsum) {
    int b = blockIdx.x;
    if (b == 0) return;
    int base = 0;
    for (int i = 0; i < b; i++) base += bsum[i];
    int gid = b * 1024 + threadIdx.x;
    if (gid <= NN) rs[gid] += base;
}

__global__ void fill_csr(const void* ei, const int* flag, const int* __restrict__ row_start,
                         int* __restrict__ fillc, int* __restrict__ col) {
    int i = blockIdx.x * 256 + threadIdx.x;
    if (i >= EE) return;
    int is64 = *flag;
    int s = load_idx(ei, i, is64);
    int d = load_idx(ei, (long long)EE + i, is64);
    int slot = row_start[d] + atomicAdd(&fillc[d], 1);
    col[slot] = s;
}

// ---------- weight prep: split fp32 W[K][M] into f16 hi/lo, transposed [n][k], XOR-swizzled ----------
__global__ void prep_split(const float* __restrict__ W1, const float* __restrict__ W2,
                           f16* __restrict__ W1h, f16* __restrict__ W1l,
                           f16* __restrict__ W2h, f16* __restrict__ W2l) {
    int t = blockIdx.x * 256 + threadIdx.x;
    if (t < 128 * 128) {
        int k = t >> 7, n = t & 127;
        float v = W1[t];
        f16 h = (f16)v;
        f16 l = (f16)(v - (float)h);
        int idx = n * 128 + (k ^ ((n & 7) << 3));
        W1h[idx] = h; W1l[idx] = l;
    } else if (t < 128 * 128 + 128 * 64) {
        int u = t - 128 * 128;
        int k = u >> 6, n = u & 63;
        float v = W2[u];
        f16 h = (f16)v;
        f16 l = (f16)(v - (float)h);
        int idx = n * 128 + (k ^ ((n & 7) << 3));
        W2h[idx] = h; W2l[idx] = l;
    }
}

// ---------- GEMM via f16 MFMA, hi/lo split. H[N][M] = X[N][128] @ W[128][M] ----------
// Block: 256 thr = 4 waves, 16 rows/wave -> 64 rows/block. Whole split-W in LDS.
// SPLIT_A=1: X is fp32, split into ah+al (3 mfma). SPLIT_A=0: X already f16 (2 mfma).
template <int M, int SPLIT_A>
__global__ __launch_bounds__(256) void gemm_mfma(const void* __restrict__ Xv,
                                                 const f16* __restrict__ Wh,
                                                 const f16* __restrict__ Wl,
                                                 f16* __restrict__ H) {
    __shared__ f16 wsh[M * 128];
    __shared__ f16 wsl[M * 128];
    const int tid = threadIdx.x;
    for (int c = tid; c < M * 16; c += 256) {
        *(float4*)&wsh[c * 8] = ((const float4*)Wh)[c];
        *(float4*)&wsl[c * 8] = ((const float4*)Wl)[c];
    }
    __syncthreads();

    const int lane = tid & 63;
    const int wv = tid >> 6;
    const int m0 = lane & 15;   // A row within tile / B col within n-tile
    const int kg = lane >> 4;   // k-group 0..3
    int row = blockIdx.x * 64 + wv * 16 + m0;
    if (row >= NN) row = NN - 1;  // clamp; stores are guarded

    constexpr int NT = M / 16;
    f32x4 acc[NT];
    #pragma unroll
    for (int i = 0; i < NT; i++) acc[i] = (f32x4){0.f, 0.f, 0.f, 0.f};

    #pragma unroll
    for (int kt = 0; kt < 4; ++kt) {
        int k0 = kt * 32 + kg * 8;
        f16x8 ah, al;
        if (SPLIT_A) {
            const float* xr = (const float*)Xv + (size_t)row * 128 + k0;
            float xv[8];
            *(float4*)&xv[0] = *(const float4*)xr;
            *(float4*)&xv[4] = *(const float4*)(xr + 4);
            #pragma unroll
            for (int r = 0; r < 8; r++) {
                ah[r] = (f16)xv[r];
                al[r] = (f16)(xv[r] - (float)ah[r]);
            }
        } else {
            ah = *(const f16x8*)((const f16*)Xv + (size_t)row * 128 + k0);
        }
        #pragma unroll
        for (int nt = 0; nt < NT; ++nt) {
            int n = nt * 16 + m0;
            int sch = (kt * 4 + kg) ^ (n & 7);
            int off = n * 128 + sch * 8;
            f16x8 bh = *(const f16x8*)&wsh[off];
            f16x8 bl = *(const f16x8*)&wsl[off];
            acc[nt] = __builtin_amdgcn_mfma_f32_16x16x32_f16(ah, bh, acc[nt], 0, 0, 0);
            if (SPLIT_A)
                acc[nt] = __builtin_amdgcn_mfma_f32_16x16x32_f16(al, bh, acc[nt], 0, 0, 0);
            acc[nt] = __builtin_amdgcn_mfma_f32_16x16x32_f16(ah, bl, acc[nt], 0, 0, 0);
        }
    }

    // C/D layout (m89-verified): col = lane&15, row = (lane>>4)*4 + reg
    int r0 = blockIdx.x * 64 + wv * 16 + kg * 4;
    #pragma unroll
    for (int nt = 0; nt < NT; ++nt) {
        int cidx = nt * 16 + m0;
        #pragma unroll
        for (int i = 0; i < 4; i++) {
            int r = r0 + i;
            if (r < NN) H[(size_t)r * M + cidx] = (f16)acc[nt][i];
        }
    }
}

// ---------- aggregation D=128: fp16 in, fp16 out (relu). One wave per node. ----------
__global__ __launch_bounds__(256) void agg128(const f16* __restrict__ h,
                                              const int* __restrict__ rs,
                                              const int* __restrict__ col,
                                              const float* __restrict__ dinv,
                                              const float* __restrict__ bias,
                                              f16* __restrict__ out) {
    int node = (blockIdx.x * 256 + threadIdx.x) >> 6;
    int lane = threadIdx.x & 63;
    if (node >= NN) return;
    float di = dinv[node];
    f16x2 sv = ((const f16x2*)(h + (size_t)node * 128))[lane];
    float ax = (float)sv[0] * di, ay = (float)sv[1] * di;
    int s = rs[node], e = rs[node + 1];
    for (int j = s; j < e; ++j) {
        int c = col[j];
        float w = dinv[c];
        f16x2 v = ((const f16x2*)(h + (size_t)c * 128))[lane];
        ax += (float)v[0] * w;
        ay += (float)v[1] * w;
    }
    float2 bv = ((const float2*)bias)[lane];
    float ox = fmaxf(ax * di + bv.x, 0.f);
    float oy = fmaxf(ay * di + bv.y, 0.f);
    f16x2 o;
    o[0] = (f16)ox; o[1] = (f16)oy;
    ((f16x2*)(out + (size_t)node * 128))[lane] = o;
}

// ---------- aggregation D=64: fp16 in, fp32 out. 32 threads per node. ----------
__global__ __launch_bounds__(256) void agg64(const f16* __restrict__ h,
                                             const int* __restrict__ rs,
                                             const int* __restrict__ col,
                                             const float* __restrict__ dinv,
                                             const float* __restrict__ bias,
                                             float* __restrict__ out) {
    int node = (blockIdx.x * 256 + threadIdx.x) >> 5;
    int lane = threadIdx.x & 31;
    if (node >= NN) return;
    float di = dinv[node];
    f16x2 sv = ((const f16x2*)(h + (size_t)node * 64))[lane];
    float ax = (float)sv[0] * di, ay = (float)sv[1] * di;
    int s = rs[node], e = rs[node + 1];
    for (int j = s; j < e; ++j) {
        int c = col[j];
        float w = dinv[c];
        f16x2 v = ((const f16x2*)(h + (size_t)c * 64))[lane];
        ax += (float)v[0] * w;
        ay += (float)v[1] * w;
    }
    float2 bv = ((const float2*)bias)[lane];
    float2 o = make_float2(ax * di + bv.x, ay * di + bv.y);
    ((float2*)(out + (size_t)node * 64))[lane] = o;
}

extern "C" void kernel_launch(void* const* d_in, const int* in_sizes, int n_in,
                              void* d_out, int out_size, void* d_ws, size_t ws_size,
                              hipStream_t stream) {
    const float* x  = (const float*)d_in[0];
    const void*  ei = d_in[1];
    const float* W1 = (const float*)d_in[2];
    const float* b1 = (const float*)d_in[3];
    const float* W2 = (const float*)d_in[4];
    const float* b2 = (const float*)d_in[5];
    float* out = (float*)d_out;

    char* wsp = (char*)d_ws;
    size_t off = 0;
    auto alloc = [&](size_t bytes) {
        void* p = wsp + off;
        off += (bytes + 255) & ~(size_t)255;
        return p;
    };
    f16*   h1        = (f16*)alloc((size_t)NN * 128 * 2);  // gemm1 out
    f16*   a1        = (f16*)alloc((size_t)NN * 128 * 2);  // agg1 out (layer-2 input)
    f16*   h2        = (f16*)alloc((size_t)NN * 64 * 2);   // gemm2 out
    int*   col       = (int*)alloc((size_t)EE * 4);
    int*   row_start = (int*)alloc((size_t)(NN + 1) * 4);
    int*   cnt       = (int*)alloc((size_t)NN * 4);
    int*   fillc     = (int*)alloc((size_t)NN * 4);
    float* dinv      = (float*)alloc((size_t)NN * 4);
    int*   bsum      = (int*)alloc((size_t)SCAN_NBLK * 4);
    int*   flag      = (int*)alloc(256);
    f16*   W1h       = (f16*)alloc(128 * 128 * 2);
    f16*   W1l       = (f16*)alloc(128 * 128 * 2);
    f16*   W2h       = (f16*)alloc(64 * 128 * 2);
    f16*   W2l       = (f16*)alloc(64 * 128 * 2);
    (void)ws_size; (void)in_sizes; (void)n_in; (void)out_size;

    hipMemsetAsync(cnt, 0, (size_t)NN * 4, stream);
    hipMemsetAsync(fillc, 0, (size_t)NN * 4, stream);

    detect_kernel<<<1, 512, 0, stream>>>(ei, flag);
    prep_split<<<96, 256, 0, stream>>>(W1, W2, W1h, W1l, W2h, W2l);
    count_deg<<<(EE + 255) / 256, 256, 0, stream>>>(ei, flag, cnt);
    scan1<<<SCAN_NBLK, 1024, 0, stream>>>(cnt, row_start, bsum, dinv);
    scan2<<<SCAN_NBLK, 1024, 0, stream>>>(row_start, bsum);
    fill_csr<<<(EE + 255) / 256, 256, 0, stream>>>(ei, flag, row_start, fillc, col);

    gemm_mfma<128, 1><<<(NN + 63) / 64, 256, 0, stream>>>(x, W1h, W1l, h1);
    agg128<<<(NN * 64) / 256, 256, 0, stream>>>(h1, row_start, col, dinv, b1, a1);
    gemm_mfma<64, 0><<<(NN + 63) / 64, 256, 0, stream>>>(a1, W2h, W2l, h2);
    agg64<<<(NN * 32) / 256, 256, 0, stream>>>(h2, row_start, col, dinv, b2, out);
}

// Round 4
// 366.320 us; speedup vs baseline: 2.1026x; 1.2619x over previous
//
#include <hip/hip_runtime.h>

// GCN 2-layer on MI355X. CSR-by-dst gather aggregation (no float atomics),
// fp16 h storage, f16-MFMA GEMM with hi/lo split, multi-block scan.
// R3 fix: agg kernels were latency-bound (1 gather in flight per wave);
// unroll edge loop x4 with independent accumulators -> 4x MLP.

#define NN 100000
#define EE 1600000
#define SCAN_NBLK ((NN + 1023) / 1024)  // 98

typedef _Float16 f16;
typedef _Float16 f16x8 __attribute__((ext_vector_type(8)));
typedef _Float16 f16x2 __attribute__((ext_vector_type(2)));
typedef float f32x4 __attribute__((ext_vector_type(4)));

// ---------- edge dtype detection (int32 vs int64) ----------
__global__ void detect_kernel(const void* ei, int* flag) {
    __shared__ int any_nz;
    if (threadIdx.x == 0) any_nz = 0;
    __syncthreads();
    unsigned v = ((const unsigned*)ei)[2 * (size_t)threadIdx.x + 1];
    if (v != 0) atomicAdd(&any_nz, 1);
    __syncthreads();
    if (threadIdx.x == 0) *flag = (any_nz == 0) ? 1 : 0;  // 1 => int64
}

__device__ __forceinline__ int load_idx(const void* p, long long i, int is64) {
    if (is64) return (int)((const long long*)p)[i];
    return ((const int*)p)[i];
}

// ---------- CSR build ----------
__global__ void count_deg(const void* ei, const int* flag, int* cnt) {
    int i = blockIdx.x * 256 + threadIdx.x;
    if (i >= EE) return;
    int is64 = *flag;
    int d = load_idx(ei, (long long)EE + i, is64);
    atomicAdd(&cnt[d], 1);
}

// multi-block exclusive scan, phase 1: per-block Hillis-Steele; also emits dinv
__global__ __launch_bounds__(1024) void scan1(const int* __restrict__ cnt,
                                              int* __restrict__ rs,
                                              int* __restrict__ bsum,
                                              float* __restrict__ dinv) {
    __shared__ int tmp[1024];
    int tid = threadIdx.x;
    int gid = blockIdx.x * 1024 + tid;
    int v = (gid < NN) ? cnt[gid] : 0;
    if (gid < NN) dinv[gid] = rsqrtf((float)(v + 1));  // +1 = self loop
    tmp[tid] = v;
    __syncthreads();
    #pragma unroll
    for (int off = 1; off < 1024; off <<= 1) {
        int t = (tid >= off) ? tmp[tid - off] : 0;
        __syncthreads();
        if (tid >= off) tmp[tid] += t;
        __syncthreads();
    }
    if (gid <= NN) rs[gid] = tmp[tid] - v;  // exclusive
    if (tid == 1023) bsum[blockIdx.x] = tmp[1023];
}

// phase 2: add block-prefix base; also seed fillc = row_start for fill_csr
__global__ __launch_bounds__(1024) void scan2(int* __restrict__ rs,
                                              const int* __restrict__ bsum,
                                              int* __restrict__ fillc) {
    int b = blockIdx.x;
    int base = 0;
    for (int i = 0; i < b; i++) base += bsum[i];
    int gid = b * 1024 + threadIdx.x;
    if (gid <= NN) {
        int v = rs[gid] + base;
        rs[gid] = v;
        if (gid < NN) fillc[gid] = v;
    }
}

__global__ void fill_csr(const void* ei, const int* flag,
                         int* __restrict__ fillc, int* __restrict__ col) {
    int i = blockIdx.x * 256 + threadIdx.x;
    if (i >= EE) return;
    int is64 = *flag;
    int s = load_idx(ei, i, is64);
    int d = load_idx(ei, (long long)EE + i, is64);
    int slot = atomicAdd(&fillc[d], 1);  // fillc pre-seeded with row_start
    col[slot] = s;
}

// ---------- weight prep: split fp32 W[K][M] into f16 hi/lo, transposed [n][k], XOR-swizzled ----------
__global__ void prep_split(const float* __restrict__ W1, const float* __restrict__ W2,
                           f16* __restrict__ W1h, f16* __restrict__ W1l,
                           f16* __restrict__ W2h, f16* __restrict__ W2l) {
    int t = blockIdx.x * 256 + threadIdx.x;
    if (t < 128 * 128) {
        int k = t >> 7, n = t & 127;
        float v = W1[t];
        f16 h = (f16)v;
        f16 l = (f16)(v - (float)h);
        int idx = n * 128 + (k ^ ((n & 7) << 3));
        W1h[idx] = h; W1l[idx] = l;
    } else if (t < 128 * 128 + 128 * 64) {
        int u = t - 128 * 128;
        int k = u >> 6, n = u & 63;
        float v = W2[u];
        f16 h = (f16)v;
        f16 l = (f16)(v - (float)h);
        int idx = n * 128 + (k ^ ((n & 7) << 3));
        W2h[idx] = h; W2l[idx] = l;
    }
}

// ---------- GEMM via f16 MFMA, hi/lo split. H[N][M] = X[N][128] @ W[128][M] ----------
template <int M, int SPLIT_A>
__global__ __launch_bounds__(256) void gemm_mfma(const void* __restrict__ Xv,
                                                 const f16* __restrict__ Wh,
                                                 const f16* __restrict__ Wl,
                                                 f16* __restrict__ H) {
    __shared__ f16 wsh[M * 128];
    __shared__ f16 wsl[M * 128];
    const int tid = threadIdx.x;
    for (int c = tid; c < M * 16; c += 256) {
        *(float4*)&wsh[c * 8] = ((const float4*)Wh)[c];
        *(float4*)&wsl[c * 8] = ((const float4*)Wl)[c];
    }
    __syncthreads();

    const int lane = tid & 63;
    const int wv = tid >> 6;
    const int m0 = lane & 15;
    const int kg = lane >> 4;
    int row = blockIdx.x * 64 + wv * 16 + m0;
    if (row >= NN) row = NN - 1;  // clamp; stores are guarded

    constexpr int NT = M / 16;
    f32x4 acc[NT];
    #pragma unroll
    for (int i = 0; i < NT; i++) acc[i] = (f32x4){0.f, 0.f, 0.f, 0.f};

    #pragma unroll
    for (int kt = 0; kt < 4; ++kt) {
        int k0 = kt * 32 + kg * 8;
        f16x8 ah, al;
        if (SPLIT_A) {
            const float* xr = (const float*)Xv + (size_t)row * 128 + k0;
            float xv[8];
            *(float4*)&xv[0] = *(const float4*)xr;
            *(float4*)&xv[4] = *(const float4*)(xr + 4);
            #pragma unroll
            for (int r = 0; r < 8; r++) {
                ah[r] = (f16)xv[r];
                al[r] = (f16)(xv[r] - (float)ah[r]);
            }
        } else {
            ah = *(const f16x8*)((const f16*)Xv + (size_t)row * 128 + k0);
        }
        #pragma unroll
        for (int nt = 0; nt < NT; ++nt) {
            int n = nt * 16 + m0;
            int sch = (kt * 4 + kg) ^ (n & 7);
            int off = n * 128 + sch * 8;
            f16x8 bh = *(const f16x8*)&wsh[off];
            f16x8 bl = *(const f16x8*)&wsl[off];
            acc[nt] = __builtin_amdgcn_mfma_f32_16x16x32_f16(ah, bh, acc[nt], 0, 0, 0);
            if (SPLIT_A)
                acc[nt] = __builtin_amdgcn_mfma_f32_16x16x32_f16(al, bh, acc[nt], 0, 0, 0);
            acc[nt] = __builtin_amdgcn_mfma_f32_16x16x32_f16(ah, bl, acc[nt], 0, 0, 0);
        }
    }

    // C/D layout (m89-verified): col = lane&15, row = (lane>>4)*4 + reg
    int r0 = blockIdx.x * 64 + wv * 16 + kg * 4;
    #pragma unroll
    for (int nt = 0; nt < NT; ++nt) {
        int cidx = nt * 16 + m0;
        #pragma unroll
        for (int i = 0; i < 4; i++) {
            int r = r0 + i;
            if (r < NN) H[(size_t)r * M + cidx] = (f16)acc[nt][i];
        }
    }
}

// ---------- aggregation D=128: fp16 in, fp16 out (relu). One wave per node, 4x MLP. ----------
__global__ __launch_bounds__(256) void agg128(const f16* __restrict__ h,
                                              const int* __restrict__ rs,
                                              const int* __restrict__ col,
                                              const float* __restrict__ dinv,
                                              const float* __restrict__ bias,
                                              f16* __restrict__ out) {
    int node = (blockIdx.x * 256 + threadIdx.x) >> 6;
    int lane = threadIdx.x & 63;
    if (node >= NN) return;
    float di = dinv[node];
    const f16x2* hp = (const f16x2*)h;
    f16x2 sv = hp[(size_t)node * 64 + lane];
    float ax = (float)sv[0] * di, ay = (float)sv[1] * di;
    int s = rs[node], e = rs[node + 1];
    float a0x = 0.f, a0y = 0.f, a1x = 0.f, a1y = 0.f;
    float a2x = 0.f, a2y = 0.f, a3x = 0.f, a3y = 0.f;
    int j = s;
    for (; j + 4 <= e; j += 4) {
        int c0 = col[j], c1 = col[j + 1], c2 = col[j + 2], c3 = col[j + 3];
        float w0 = dinv[c0], w1 = dinv[c1], w2 = dinv[c2], w3 = dinv[c3];
        f16x2 v0 = hp[(size_t)c0 * 64 + lane];
        f16x2 v1 = hp[(size_t)c1 * 64 + lane];
        f16x2 v2 = hp[(size_t)c2 * 64 + lane];
        f16x2 v3 = hp[(size_t)c3 * 64 + lane];
        a0x += (float)v0[0] * w0; a0y += (float)v0[1] * w0;
        a1x += (float)v1[0] * w1; a1y += (float)v1[1] * w1;
        a2x += (float)v2[0] * w2; a2y += (float)v2[1] * w2;
        a3x += (float)v3[0] * w3; a3y += (float)v3[1] * w3;
    }
    for (; j < e; ++j) {
        int c = col[j];
        float w = dinv[c];
        f16x2 v = hp[(size_t)c * 64 + lane];
        a0x += (float)v[0] * w; a0y += (float)v[1] * w;
    }
    ax += (a0x + a1x) + (a2x + a3x);
    ay += (a0y + a1y) + (a2y + a3y);
    float2 bv = ((const float2*)bias)[lane];
    float ox = fmaxf(ax * di + bv.x, 0.f);
    float oy = fmaxf(ay * di + bv.y, 0.f);
    f16x2 o;
    o[0] = (f16)ox; o[1] = (f16)oy;
    ((f16x2*)(out + (size_t)node * 128))[lane] = o;
}

// ---------- aggregation D=64: fp16 in, fp32 out. 32 threads per node, 4x MLP. ----------
__global__ __launch_bounds__(256) void agg64(const f16* __restrict__ h,
                                             const int* __restrict__ rs,
                                             const int* __restrict__ col,
                                             const float* __restrict__ dinv,
                                             const float* __restrict__ bias,
                                             float* __restrict__ out) {
    int node = (blockIdx.x * 256 + threadIdx.x) >> 5;
    int lane = threadIdx.x & 31;
    if (node >= NN) return;
    float di = dinv[node];
    const f16x2* hp = (const f16x2*)h;
    f16x2 sv = hp[(size_t)node * 32 + lane];
    float ax = (float)sv[0] * di, ay = (float)sv[1] * di;
    int s = rs[node], e = rs[node + 1];
    float a0x = 0.f, a0y = 0.f, a1x = 0.f, a1y = 0.f;
    float a2x = 0.f, a2y = 0.f, a3x = 0.f, a3y = 0.f;
    int j = s;
    for (; j + 4 <= e; j += 4) {
        int c0 = col[j], c1 = col[j + 1], c2 = col[j + 2], c3 = col[j + 3];
        float w0 = dinv[c0], w1 = dinv[c1], w2 = dinv[c2], w3 = dinv[c3];
        f16x2 v0 = hp[(size_t)c0 * 32 + lane];
        f16x2 v1 = hp[(size_t)c1 * 32 + lane];
        f16x2 v2 = hp[(size_t)c2 * 32 + lane];
        f16x2 v3 = hp[(size_t)c3 * 32 + lane];
        a0x += (float)v0[0] * w0; a0y += (float)v0[1] * w0;
        a1x += (float)v1[0] * w1; a1y += (float)v1[1] * w1;
        a2x += (float)v2[0] * w2; a2y += (float)v2[1] * w2;
        a3x += (float)v3[0] * w3; a3y += (float)v3[1] * w3;
    }
    for (; j < e; ++j) {
        int c = col[j];
        float w = dinv[c];
        f16x2 v = hp[(size_t)c * 32 + lane];
        a0x += (float)v[0] * w; a0y += (float)v[1] * w;
    }
    ax += (a0x + a1x) + (a2x + a3x);
    ay += (a0y + a1y) + (a2y + a3y);
    float2 bv = ((const float2*)bias)[lane];
    float2 o = make_float2(ax * di + bv.x, ay * di + bv.y);
    ((float2*)(out + (size_t)node * 64))[lane] = o;
}

extern "C" void kernel_launch(void* const* d_in, const int* in_sizes, int n_in,
                              void* d_out, int out_size, void* d_ws, size_t ws_size,
                              hipStream_t stream) {
    const float* x  = (const float*)d_in[0];
    const void*  ei = d_in[1];
    const float* W1 = (const float*)d_in[2];
    const float* b1 = (const float*)d_in[3];
    const float* W2 = (const float*)d_in[4];
    const float* b2 = (const float*)d_in[5];
    float* out = (float*)d_out;

    char* wsp = (char*)d_ws;
    size_t off = 0;
    auto alloc = [&](size_t bytes) {
        void* p = wsp + off;
        off += (bytes + 255) & ~(size_t)255;
        return p;
    };
    f16*   h1        = (f16*)alloc((size_t)NN * 128 * 2);  // gemm1 out
    f16*   a1        = (f16*)alloc((size_t)NN * 128 * 2);  // agg1 out (layer-2 input)
    f16*   h2        = (f16*)alloc((size_t)NN * 64 * 2);   // gemm2 out
    int*   col       = (int*)alloc((size_t)EE * 4);
    int*   row_start = (int*)alloc((size_t)(NN + 1) * 4);
    int*   cnt       = (int*)alloc((size_t)NN * 4);
    int*   fillc     = (int*)alloc((size_t)NN * 4);
    float* dinv      = (float*)alloc((size_t)NN * 4);
    int*   bsum      = (int*)alloc((size_t)SCAN_NBLK * 4);
    int*   flag      = (int*)alloc(256);
    f16*   W1h       = (f16*)alloc(128 * 128 * 2);
    f16*   W1l       = (f16*)alloc(128 * 128 * 2);
    f16*   W2h       = (f16*)alloc(64 * 128 * 2);
    f16*   W2l       = (f16*)alloc(64 * 128 * 2);
    (void)ws_size; (void)in_sizes; (void)n_in; (void)out_size;

    hipMemsetAsync(cnt, 0, (size_t)NN * 4, stream);

    detect_kernel<<<1, 512, 0, stream>>>(ei, flag);
    prep_split<<<96, 256, 0, stream>>>(W1, W2, W1h, W1l, W2h, W2l);
    count_deg<<<(EE + 255) / 256, 256, 0, stream>>>(ei, flag, cnt);
    scan1<<<SCAN_NBLK, 1024, 0, stream>>>(cnt, row_start, bsum, dinv);
    scan2<<<SCAN_NBLK, 1024, 0, stream>>>(row_start, bsum, fillc);
    fill_csr<<<(EE + 255) / 256, 256, 0, stream>>>(ei, flag, fillc, col);

    gemm_mfma<128, 1><<<(NN + 63) / 64, 256, 0, stream>>>(x, W1h, W1l, h1);
    agg128<<<(NN * 64) / 256, 256, 0, stream>>>(h1, row_start, col, dinv, b1, a1);
    gemm_mfma<64, 0><<<(NN + 63) / 64, 256, 0, stream>>>(a1, W2h, W2l, h2);
    agg64<<<(NN * 32) / 256, 256, 0, stream>>>(h2, row_start, col, dinv, b2, out);
}

// Round 5
// 225.819 us; speedup vs baseline: 3.4108x; 1.6222x over previous
//
#include <hip/hip_runtime.h>

// GCN 2-layer on MI355X. fp16 h storage, f16-MFMA GEMM with hi/lo split,
// 4x-MLP gather aggregation. R4 fix: CSR build had 16x write amplification
// (random 4B scatter across 8 XCD L2s, 105MB HBM writes for a 6.4MB array).
// Replaced with bucket partition (391 buckets of 256 nodes): partition pass
// writes bucket-major 4B payloads in contiguous runs; per-bucket fill keeps
// counts/cursors in LDS and scatters col within a 16KB single-XCD window.

#define NN 100000
#define EE 1600000
#define NB 391            // buckets of 256 nodes: 391*256 = 100096 >= NN
#define EPB 8192          // edges per partition block
#define PBLK ((EE + EPB - 1) / EPB)  // 196

typedef _Float16 f16;
typedef _Float16 f16x8 __attribute__((ext_vector_type(8)));
typedef _Float16 f16x2 __attribute__((ext_vector_type(2)));
typedef float f32x4 __attribute__((ext_vector_type(4)));

// ---------- edge dtype detection (int32 vs int64) ----------
__global__ void detect_kernel(const void* ei, int* flag) {
    __shared__ int any_nz;
    if (threadIdx.x == 0) any_nz = 0;
    __syncthreads();
    unsigned v = ((const unsigned*)ei)[2 * (size_t)threadIdx.x + 1];
    if (v != 0) atomicAdd(&any_nz, 1);
    __syncthreads();
    if (threadIdx.x == 0) *flag = (any_nz == 0) ? 1 : 0;  // 1 => int64
}

__device__ __forceinline__ int load_idx(const void* p, long long i, int is64) {
    if (is64) return (int)((const long long*)p)[i];
    return ((const int*)p)[i];
}

// ---------- bucket histogram ----------
__global__ __launch_bounds__(256) void hist_kernel(const void* ei, const int* flag,
                                                   int* __restrict__ bucket_cnt) {
    __shared__ int lh[NB];
    for (int i = threadIdx.x; i < NB; i += 256) lh[i] = 0;
    __syncthreads();
    int is64 = *flag;
    long long base = (long long)blockIdx.x * EPB;
    #pragma unroll 4
    for (int k = 0; k < EPB / 256; k++) {
        long long i = base + k * 256 + threadIdx.x;
        if (i < EE) {
            int d = load_idx(ei, (long long)EE + i, is64);
            atomicAdd(&lh[d >> 8], 1);
        }
    }
    __syncthreads();
    for (int i = threadIdx.x; i < NB; i += 256)
        if (lh[i]) atomicAdd(&bucket_cnt[i], lh[i]);
}

// ---------- bucket base scan (tiny) ----------
__global__ __launch_bounds__(512) void bucket_scan(const int* __restrict__ bucket_cnt,
                                                   int* __restrict__ bucket_base,
                                                   int* __restrict__ bucket_fill) {
    __shared__ int tmp[512];
    int tid = threadIdx.x;
    int v = (tid < NB) ? bucket_cnt[tid] : 0;
    tmp[tid] = v;
    __syncthreads();
    #pragma unroll
    for (int off = 1; off < 512; off <<= 1) {
        int t = (tid >= off) ? tmp[tid - off] : 0;
        __syncthreads();
        if (tid >= off) tmp[tid] += t;
        __syncthreads();
    }
    if (tid < NB) {
        int b = tmp[tid] - v;
        bucket_base[tid] = b;
        bucket_fill[tid] = b;
    }
    if (tid == NB - 1) bucket_base[NB] = tmp[tid];
}

// ---------- partition: edges -> bucket-major packed payloads ----------
__global__ __launch_bounds__(256) void partition_kernel(const void* ei, const int* flag,
                                                        int* __restrict__ bucket_fill,
                                                        unsigned* __restrict__ col32) {
    __shared__ int lh[NB], lbase[NB], lfill[NB];
    for (int i = threadIdx.x; i < NB; i += 256) { lh[i] = 0; lfill[i] = 0; }
    __syncthreads();
    int is64 = *flag;
    long long base = (long long)blockIdx.x * EPB;
    #pragma unroll 4
    for (int k = 0; k < EPB / 256; k++) {
        long long i = base + k * 256 + threadIdx.x;
        if (i < EE) {
            int d = load_idx(ei, (long long)EE + i, is64);
            atomicAdd(&lh[d >> 8], 1);
        }
    }
    __syncthreads();
    for (int i = threadIdx.x; i < NB; i += 256)
        lbase[i] = lh[i] ? atomicAdd(&bucket_fill[i], lh[i]) : 0;
    __syncthreads();
    #pragma unroll 4
    for (int k = 0; k < EPB / 256; k++) {
        long long i = base + k * 256 + threadIdx.x;
        if (i < EE) {
            int s = load_idx(ei, i, is64);
            int d = load_idx(ei, (long long)EE + i, is64);
            int b = d >> 8;
            int r = atomicAdd(&lfill[b], 1);
            col32[lbase[b] + r] = ((unsigned)s << 8) | (unsigned)(d & 255);
        }
    }
}

// ---------- per-bucket fill: counts+cursors in LDS, emits rs/dinv/col ----------
__global__ __launch_bounds__(256) void bucket_fill_kernel(const unsigned* __restrict__ col32,
                                                          const int* __restrict__ bucket_base,
                                                          int* __restrict__ rs,
                                                          float* __restrict__ dinv,
                                                          int* __restrict__ col) {
    __shared__ int cnt[256], incl[256], lfill[256];
    __shared__ int sbase, send;
    int t = threadIdx.x, b = blockIdx.x;
    cnt[t] = 0; lfill[t] = 0;
    if (t == 0) { sbase = bucket_base[b]; send = bucket_base[b + 1]; }
    __syncthreads();
    int base = sbase, end = send;
    for (int i = base + t; i < end; i += 256)
        atomicAdd(&cnt[col32[i] & 255u], 1);
    __syncthreads();
    incl[t] = cnt[t];
    __syncthreads();
    #pragma unroll
    for (int off = 1; off < 256; off <<= 1) {
        int v = (t >= off) ? incl[t - off] : 0;
        __syncthreads();
        if (t >= off) incl[t] += v;
        __syncthreads();
    }
    int node = b * 256 + t;
    int excl = (t == 0) ? 0 : incl[t - 1];
    if (node < NN) {
        rs[node] = base + excl;
        dinv[node] = rsqrtf((float)(cnt[t] + 1));  // +1 = self loop
    }
    if (node == NN) rs[NN] = base + excl;  // NN = 390*256+160 lands in bucket 390
    __syncthreads();
    for (int i = base + t; i < end; i += 256) {
        unsigned p = col32[i];
        int d = p & 255u;
        int r = atomicAdd(&lfill[d], 1);
        int ex = (d == 0) ? 0 : incl[d - 1];
        col[base + ex + r] = (int)(p >> 8);
    }
}

// ---------- weight prep: split fp32 W[K][M] into f16 hi/lo, transposed [n][k], XOR-swizzled ----------
__global__ void prep_split(const float* __restrict__ W1, const float* __restrict__ W2,
                           f16* __restrict__ W1h, f16* __restrict__ W1l,
                           f16* __restrict__ W2h, f16* __restrict__ W2l) {
    int t = blockIdx.x * 256 + threadIdx.x;
    if (t < 128 * 128) {
        int k = t >> 7, n = t & 127;
        float v = W1[t];
        f16 h = (f16)v;
        f16 l = (f16)(v - (float)h);
        int idx = n * 128 + (k ^ ((n & 7) << 3));
        W1h[idx] = h; W1l[idx] = l;
    } else if (t < 128 * 128 + 128 * 64) {
        int u = t - 128 * 128;
        int k = u >> 6, n = u & 63;
        float v = W2[u];
        f16 h = (f16)v;
        f16 l = (f16)(v - (float)h);
        int idx = n * 128 + (k ^ ((n & 7) << 3));
        W2h[idx] = h; W2l[idx] = l;
    }
}

// ---------- GEMM via f16 MFMA, hi/lo split. H[N][M] = X[N][128] @ W[128][M] ----------
template <int M, int SPLIT_A>
__global__ __launch_bounds__(256) void gemm_mfma(const void* __restrict__ Xv,
                                                 const f16* __restrict__ Wh,
                                                 const f16* __restrict__ Wl,
                                                 f16* __restrict__ H) {
    __shared__ f16 wsh[M * 128];
    __shared__ f16 wsl[M * 128];
    const int tid = threadIdx.x;
    for (int c = tid; c < M * 16; c += 256) {
        *(float4*)&wsh[c * 8] = ((const float4*)Wh)[c];
        *(float4*)&wsl[c * 8] = ((const float4*)Wl)[c];
    }
    __syncthreads();

    const int lane = tid & 63;
    const int wv = tid >> 6;
    const int m0 = lane & 15;
    const int kg = lane >> 4;
    int row = blockIdx.x * 64 + wv * 16 + m0;
    if (row >= NN) row = NN - 1;  // clamp; stores are guarded

    constexpr int NT = M / 16;
    f32x4 acc[NT];
    #pragma unroll
    for (int i = 0; i < NT; i++) acc[i] = (f32x4){0.f, 0.f, 0.f, 0.f};

    #pragma unroll
    for (int kt = 0; kt < 4; ++kt) {
        int k0 = kt * 32 + kg * 8;
        f16x8 ah, al;
        if (SPLIT_A) {
            const float* xr = (const float*)Xv + (size_t)row * 128 + k0;
            float xv[8];
            *(float4*)&xv[0] = *(const float4*)xr;
            *(float4*)&xv[4] = *(const float4*)(xr + 4);
            #pragma unroll
            for (int r = 0; r < 8; r++) {
                ah[r] = (f16)xv[r];
                al[r] = (f16)(xv[r] - (float)ah[r]);
            }
        } else {
            ah = *(const f16x8*)((const f16*)Xv + (size_t)row * 128 + k0);
        }
        #pragma unroll
        for (int nt = 0; nt < NT; ++nt) {
            int n = nt * 16 + m0;
            int sch = (kt * 4 + kg) ^ (n & 7);
            int off = n * 128 + sch * 8;
            f16x8 bh = *(const f16x8*)&wsh[off];
            f16x8 bl = *(const f16x8*)&wsl[off];
            acc[nt] = __builtin_amdgcn_mfma_f32_16x16x32_f16(ah, bh, acc[nt], 0, 0, 0);
            if (SPLIT_A)
                acc[nt] = __builtin_amdgcn_mfma_f32_16x16x32_f16(al, bh, acc[nt], 0, 0, 0);
            acc[nt] = __builtin_amdgcn_mfma_f32_16x16x32_f16(ah, bl, acc[nt], 0, 0, 0);
        }
    }

    // C/D layout (m89-verified): col = lane&15, row = (lane>>4)*4 + reg
    int r0 = blockIdx.x * 64 + wv * 16 + kg * 4;
    #pragma unroll
    for (int nt = 0; nt < NT; ++nt) {
        int cidx = nt * 16 + m0;
        #pragma unroll
        for (int i = 0; i < 4; i++) {
            int r = r0 + i;
            if (r < NN) H[(size_t)r * M + cidx] = (f16)acc[nt][i];
        }
    }
}

// ---------- aggregation D=128: fp16 in, fp16 out (relu). One wave per node, 4x MLP. ----------
__global__ __launch_bounds__(256) void agg128(const f16* __restrict__ h,
                                              const int* __restrict__ rs,
                                              const int* __restrict__ col,
                                              const float* __restrict__ dinv,
                                              const float* __restrict__ bias,
                                              f16* __restrict__ out) {
    int node = (blockIdx.x * 256 + threadIdx.x) >> 6;
    int lane = threadIdx.x & 63;
    if (node >= NN) return;
    float di = dinv[node];
    const f16x2* hp = (const f16x2*)h;
    f16x2 sv = hp[(size_t)node * 64 + lane];
    float ax = (float)sv[0] * di, ay = (float)sv[1] * di;
    int s = rs[node], e = rs[node + 1];
    float a0x = 0.f, a0y = 0.f, a1x = 0.f, a1y = 0.f;
    float a2x = 0.f, a2y = 0.f, a3x = 0.f, a3y = 0.f;
    int j = s;
    for (; j + 4 <= e; j += 4) {
        int c0 = col[j], c1 = col[j + 1], c2 = col[j + 2], c3 = col[j + 3];
        float w0 = dinv[c0], w1 = dinv[c1], w2 = dinv[c2], w3 = dinv[c3];
        f16x2 v0 = hp[(size_t)c0 * 64 + lane];
        f16x2 v1 = hp[(size_t)c1 * 64 + lane];
        f16x2 v2 = hp[(size_t)c2 * 64 + lane];
        f16x2 v3 = hp[(size_t)c3 * 64 + lane];
        a0x += (float)v0[0] * w0; a0y += (float)v0[1] * w0;
        a1x += (float)v1[0] * w1; a1y += (float)v1[1] * w1;
        a2x += (float)v2[0] * w2; a2y += (float)v2[1] * w2;
        a3x += (float)v3[0] * w3; a3y += (float)v3[1] * w3;
    }
    for (; j < e; ++j) {
        int c = col[j];
        float w = dinv[c];
        f16x2 v = hp[(size_t)c * 64 + lane];
        a0x += (float)v[0] * w; a0y += (float)v[1] * w;
    }
    ax += (a0x + a1x) + (a2x + a3x);
    ay += (a0y + a1y) + (a2y + a3y);
    float2 bv = ((const float2*)bias)[lane];
    float ox = fmaxf(ax * di + bv.x, 0.f);
    float oy = fmaxf(ay * di + bv.y, 0.f);
    f16x2 o;
    o[0] = (f16)ox; o[1] = (f16)oy;
    ((f16x2*)(out + (size_t)node * 128))[lane] = o;
}

// ---------- aggregation D=64: fp16 in, fp32 out. 32 threads per node, 4x MLP. ----------
__global__ __launch_bounds__(256) void agg64(const f16* __restrict__ h,
                                             const int* __restrict__ rs,
                                             const int* __restrict__ col,
                                             const float* __restrict__ dinv,
                                             const float* __restrict__ bias,
                                             float* __restrict__ out) {
    int node = (blockIdx.x * 256 + threadIdx.x) >> 5;
    int lane = threadIdx.x & 31;
    if (node >= NN) return;
    float di = dinv[node];
    const f16x2* hp = (const f16x2*)h;
    f16x2 sv = hp[(size_t)node * 32 + lane];
    float ax = (float)sv[0] * di, ay = (float)sv[1] * di;
    int s = rs[node], e = rs[node + 1];
    float a0x = 0.f, a0y = 0.f, a1x = 0.f, a1y = 0.f;
    float a2x = 0.f, a2y = 0.f, a3x = 0.f, a3y = 0.f;
    int j = s;
    for (; j + 4 <= e; j += 4) {
        int c0 = col[j], c1 = col[j + 1], c2 = col[j + 2], c3 = col[j + 3];
        float w0 = dinv[c0], w1 = dinv[c1], w2 = dinv[c2], w3 = dinv[c3];
        f16x2 v0 = hp[(size_t)c0 * 32 + lane];
        f16x2 v1 = hp[(size_t)c1 * 32 + lane];
        f16x2 v2 = hp[(size_t)c2 * 32 + lane];
        f16x2 v3 = hp[(size_t)c3 * 32 + lane];
        a0x += (float)v0[0] * w0; a0y += (float)v0[1] * w0;
        a1x += (float)v1[0] * w1; a1y += (float)v1[1] * w1;
        a2x += (float)v2[0] * w2; a2y += (float)v2[1] * w2;
        a3x += (float)v3[0] * w3; a3y += (float)v3[1] * w3;
    }
    for (; j < e; ++j) {
        int c = col[j];
        float w = dinv[c];
        f16x2 v = hp[(size_t)c * 32 + lane];
        a0x += (float)v[0] * w; a0y += (float)v[1] * w;
    }
    ax += (a0x + a1x) + (a2x + a3x);
    ay += (a0y + a1y) + (a2y + a3y);
    float2 bv = ((const float2*)bias)[lane];
    float2 o = make_float2(ax * di + bv.x, ay * di + bv.y);
    ((float2*)(out + (size_t)node * 64))[lane] = o;
}

extern "C" void kernel_launch(void* const* d_in, const int* in_sizes, int n_in,
                              void* d_out, int out_size, void* d_ws, size_t ws_size,
                              hipStream_t stream) {
    const float* x  = (const float*)d_in[0];
    const void*  ei = d_in[1];
    const float* W1 = (const float*)d_in[2];
    const float* b1 = (const float*)d_in[3];
    const float* W2 = (const float*)d_in[4];
    const float* b2 = (const float*)d_in[5];
    float* out = (float*)d_out;

    char* wsp = (char*)d_ws;
    size_t off = 0;
    auto alloc = [&](size_t bytes) {
        void* p = wsp + off;
        off += (bytes + 255) & ~(size_t)255;
        return p;
    };
    f16*      h1          = (f16*)alloc((size_t)NN * 128 * 2);  // gemm1 out
    f16*      a1          = (f16*)alloc((size_t)NN * 128 * 2);  // agg1 out (layer-2 input)
    f16*      h2          = (f16*)alloc((size_t)NN * 64 * 2);   // gemm2 out
    unsigned* col32       = (unsigned*)alloc((size_t)EE * 4);   // bucket-major payloads
    int*      col         = (int*)alloc((size_t)EE * 4);
    int*      row_start   = (int*)alloc((size_t)(NN + 1) * 4);
    float*    dinv        = (float*)alloc((size_t)NN * 4);
    int*      bucket_cnt  = (int*)alloc((size_t)NB * 4);
    int*      bucket_base = (int*)alloc((size_t)(NB + 1) * 4);
    int*      bucket_fill = (int*)alloc((size_t)NB * 4);
    int*      flag        = (int*)alloc(256);
    f16*      W1h         = (f16*)alloc(128 * 128 * 2);
    f16*      W1l         = (f16*)alloc(128 * 128 * 2);
    f16*      W2h         = (f16*)alloc(64 * 128 * 2);
    f16*      W2l         = (f16*)alloc(64 * 128 * 2);
    (void)ws_size; (void)in_sizes; (void)n_in; (void)out_size;

    hipMemsetAsync(bucket_cnt, 0, (size_t)NB * 4, stream);

    detect_kernel<<<1, 512, 0, stream>>>(ei, flag);
    prep_split<<<96, 256, 0, stream>>>(W1, W2, W1h, W1l, W2h, W2l);
    hist_kernel<<<PBLK, 256, 0, stream>>>(ei, flag, bucket_cnt);
    bucket_scan<<<1, 512, 0, stream>>>(bucket_cnt, bucket_base, bucket_fill);
    partition_kernel<<<PBLK, 256, 0, stream>>>(ei, flag, bucket_fill, col32);
    bucket_fill_kernel<<<NB, 256, 0, stream>>>(col32, bucket_base, row_start, dinv, col);

    gemm_mfma<128, 1><<<(NN + 63) / 64, 256, 0, stream>>>(x, W1h, W1l, h1);
    agg128<<<(NN * 64) / 256, 256, 0, stream>>>(h1, row_start, col, dinv, b1, a1);
    gemm_mfma<64, 0><<<(NN + 63) / 64, 256, 0, stream>>>(a1, W2h, W2l, h2);
    agg64<<<(NN * 32) / 256, 256, 0, stream>>>(h2, row_start, col, dinv, b2, out);
}

// Round 6
// 197.020 us; speedup vs baseline: 3.9093x; 1.1462x over previous
//
#include <hip/hip_runtime.h>

// GCN 2-layer on MI355X. fp16 h storage, f16-MFMA GEMM with hi/lo split,
// bucket-partitioned CSR build, 8-wide software-pipelined gather aggregation.
// R5: (1) adjacency padded to multiple of 8 (sentinel src=NN, dinv[NN]=0,
// h[NN] zeroed) -> no serial tail, 8 gathers in flight; (2) next-batch col
// prefetch breaks the col->dinv->gather serial chain; (3) fixed-capacity
// buckets remove hist/scan/detect kernels entirely.

#define NN 100000
#define EE 1600000
#define NB 391              // buckets of 256 nodes
#define BCAP 4608           // raw col32 slots per bucket (mean 4092, +8 sigma)
#define PCAP 6656           // padded col slots per bucket (mean ~5884 + slack)
#define EPB 8192            // edges per partition block
#define PBLK ((EE + EPB - 1) / EPB)  // 196

typedef _Float16 f16;
typedef _Float16 f16x8 __attribute__((ext_vector_type(8)));
typedef _Float16 f16x2 __attribute__((ext_vector_type(2)));
typedef float f32x4 __attribute__((ext_vector_type(4)));

__device__ __forceinline__ int load_idx(const void* p, long long i, int is64) {
    if (is64) return (int)((const long long*)p)[i];
    return ((const int*)p)[i];
}

// ---------- bucket cursor init ----------
__global__ void init_buckets(int* cursor) {
    int i = blockIdx.x * 256 + threadIdx.x;
    if (i < NB) cursor[i] = i * BCAP;
}

// ---------- partition: edges -> bucket-major packed payloads (fixed-cap) ----------
__global__ __launch_bounds__(256) void partition_kernel(const void* ei,
                                                        int* __restrict__ cursor,
                                                        unsigned* __restrict__ col32) {
    __shared__ int lh[NB], lbase[NB], lfill[NB];
    __shared__ int s_is64;
    for (int i = threadIdx.x; i < NB; i += 256) { lh[i] = 0; lfill[i] = 0; }
    if (threadIdx.x == 0) {
        // int64 detect: odd 32-bit words of non-negative int64 values are 0
        const unsigned* w = (const unsigned*)ei;
        unsigned acc = 0;
        #pragma unroll
        for (int k = 0; k < 8; k++) acc |= w[2 * (k * 997 + 1) + 1];
        s_is64 = (acc == 0);
    }
    __syncthreads();
    int is64 = s_is64;
    long long base = (long long)blockIdx.x * EPB;
    #pragma unroll 4
    for (int k = 0; k < EPB / 256; k++) {
        long long i = base + k * 256 + threadIdx.x;
        if (i < EE) {
            int d = load_idx(ei, (long long)EE + i, is64);
            atomicAdd(&lh[d >> 8], 1);
        }
    }
    __syncthreads();
    for (int i = threadIdx.x; i < NB; i += 256)
        lbase[i] = lh[i] ? atomicAdd(&cursor[i], lh[i]) : 0;
    __syncthreads();
    #pragma unroll 4
    for (int k = 0; k < EPB / 256; k++) {
        long long i = base + k * 256 + threadIdx.x;
        if (i < EE) {
            int s = load_idx(ei, i, is64);
            int d = load_idx(ei, (long long)EE + i, is64);
            int b = d >> 8;
            int r = atomicAdd(&lfill[b], 1);
            col32[lbase[b] + r] = ((unsigned)s << 8) | (unsigned)(d & 255);
        }
    }
}

// ---------- per-bucket fill: counts/cursors in LDS; emits rsp/dinv/padded col ----------
__global__ __launch_bounds__(256) void bucket_fill_kernel(const unsigned* __restrict__ col32,
                                                          const int* __restrict__ cursor,
                                                          int2* __restrict__ rsp,
                                                          float* __restrict__ dinv,
                                                          int* __restrict__ col) {
    __shared__ int cnt[256], incl[256], lfill[256];
    int t = threadIdx.x, b = blockIdx.x;
    cnt[t] = 0; lfill[t] = 0;
    __syncthreads();
    int base = b * BCAP;
    int end = cursor[b];  // base + edges_in_bucket
    for (int i = base + t; i < end; i += 256)
        atomicAdd(&cnt[col32[i] & 255u], 1);
    __syncthreads();
    int pc = (cnt[t] + 7) & ~7;  // padded degree (multiple of 8)
    incl[t] = pc;
    __syncthreads();
    #pragma unroll
    for (int off = 1; off < 256; off <<= 1) {
        int v = (t >= off) ? incl[t - off] : 0;
        __syncthreads();
        if (t >= off) incl[t] += v;
        __syncthreads();
    }
    int node = b * 256 + t;
    int excl = (t == 0) ? 0 : incl[t - 1];
    int myrs = b * PCAP + excl;
    if (node < NN) {
        rsp[node] = make_int2(myrs, pc);
        dinv[node] = rsqrtf((float)(cnt[t] + 1));  // +1 = self loop
    }
    if (b == 0 && t == 0) dinv[NN] = 0.f;  // sentinel weight
    __syncthreads();
    for (int i = base + t; i < end; i += 256) {
        unsigned p = col32[i];
        int d = p & 255u;
        int r = atomicAdd(&lfill[d], 1);
        int ex = (d == 0) ? 0 : incl[d - 1];
        col[b * PCAP + ex + r] = (int)(p >> 8);
    }
    __syncthreads();
    int cn = cnt[t];
    for (int k = cn; k < ((cn + 7) & ~7); k++) col[myrs + k] = NN;  // pad slots
}

// ---------- weight prep: split fp32 W[K][M] into f16 hi/lo, transposed [n][k], XOR-swizzled ----------
__global__ void prep_split(const float* __restrict__ W1, const float* __restrict__ W2,
                           f16* __restrict__ W1h, f16* __restrict__ W1l,
                           f16* __restrict__ W2h, f16* __restrict__ W2l) {
    int t = blockIdx.x * 256 + threadIdx.x;
    if (t < 128 * 128) {
        int k = t >> 7, n = t & 127;
        float v = W1[t];
        f16 h = (f16)v;
        f16 l = (f16)(v - (float)h);
        int idx = n * 128 + (k ^ ((n & 7) << 3));
        W1h[idx] = h; W1l[idx] = l;
    } else if (t < 128 * 128 + 128 * 64) {
        int u = t - 128 * 128;
        int k = u >> 6, n = u & 63;
        float v = W2[u];
        f16 h = (f16)v;
        f16 l = (f16)(v - (float)h);
        int idx = n * 128 + (k ^ ((n & 7) << 3));
        W2h[idx] = h; W2l[idx] = l;
    }
}

// ---------- GEMM via f16 MFMA, hi/lo split. H[N][M] = X[N][128] @ W[128][M] ----------
template <int M, int SPLIT_A>
__global__ __launch_bounds__(256) void gemm_mfma(const void* __restrict__ Xv,
                                                 const f16* __restrict__ Wh,
                                                 const f16* __restrict__ Wl,
                                                 f16* __restrict__ H) {
    __shared__ f16 wsh[M * 128];
    __shared__ f16 wsl[M * 128];
    const int tid = threadIdx.x;
    for (int c = tid; c < M * 16; c += 256) {
        *(float4*)&wsh[c * 8] = ((const float4*)Wh)[c];
        *(float4*)&wsl[c * 8] = ((const float4*)Wl)[c];
    }
    __syncthreads();

    const int lane = tid & 63;
    const int wv = tid >> 6;
    const int m0 = lane & 15;
    const int kg = lane >> 4;
    int row = blockIdx.x * 64 + wv * 16 + m0;
    if (row >= NN) row = NN - 1;  // clamp; stores are guarded

    constexpr int NT = M / 16;
    f32x4 acc[NT];
    #pragma unroll
    for (int i = 0; i < NT; i++) acc[i] = (f32x4){0.f, 0.f, 0.f, 0.f};

    #pragma unroll
    for (int kt = 0; kt < 4; ++kt) {
        int k0 = kt * 32 + kg * 8;
        f16x8 ah, al;
        if (SPLIT_A) {
            const float* xr = (const float*)Xv + (size_t)row * 128 + k0;
            float xv[8];
            *(float4*)&xv[0] = *(const float4*)xr;
            *(float4*)&xv[4] = *(const float4*)(xr + 4);
            #pragma unroll
            for (int r = 0; r < 8; r++) {
                ah[r] = (f16)xv[r];
                al[r] = (f16)(xv[r] - (float)ah[r]);
            }
        } else {
            ah = *(const f16x8*)((const f16*)Xv + (size_t)row * 128 + k0);
        }
        #pragma unroll
        for (int nt = 0; nt < NT; ++nt) {
            int n = nt * 16 + m0;
            int sch = (kt * 4 + kg) ^ (n & 7);
            int off = n * 128 + sch * 8;
            f16x8 bh = *(const f16x8*)&wsh[off];
            f16x8 bl = *(const f16x8*)&wsl[off];
            acc[nt] = __builtin_amdgcn_mfma_f32_16x16x32_f16(ah, bh, acc[nt], 0, 0, 0);
            if (SPLIT_A)
                acc[nt] = __builtin_amdgcn_mfma_f32_16x16x32_f16(al, bh, acc[nt], 0, 0, 0);
            acc[nt] = __builtin_amdgcn_mfma_f32_16x16x32_f16(ah, bl, acc[nt], 0, 0, 0);
        }
    }

    // C/D layout (m89-verified): col = lane&15, row = (lane>>4)*4 + reg
    int r0 = blockIdx.x * 64 + wv * 16 + kg * 4;
    #pragma unroll
    for (int nt = 0; nt < NT; ++nt) {
        int cidx = nt * 16 + m0;
        #pragma unroll
        for (int i = 0; i < 4; i++) {
            int r = r0 + i;
            if (r < NN) H[(size_t)r * M + cidx] = (f16)acc[nt][i];
        }
    }
}

// ---------- aggregation D=128: 8-wide batches, col prefetch. One wave/node. ----------
__global__ __launch_bounds__(256) void agg128(const f16* __restrict__ h,
                                              const int2* __restrict__ rsp,
                                              const int* __restrict__ col,
                                              const float* __restrict__ dinv,
                                              const float* __restrict__ bias,
                                              f16* __restrict__ out) {
    int node = (blockIdx.x * 256 + threadIdx.x) >> 6;
    int lane = threadIdx.x & 63;
    if (node >= NN) return;
    float di = dinv[node];
    const f16x2* hp = (const f16x2*)h;
    f16x2 sv = hp[(unsigned)(node * 64 + lane)];
    int2 g = rsp[node];
    int s = g.x, e = g.x + g.y;  // length multiple of 8
    float ax[8], ay[8];
    #pragma unroll
    for (int i = 0; i < 8; i++) { ax[i] = 0.f; ay[i] = 0.f; }
    int c[8];
    if (s < e) {
        #pragma unroll
        for (int i = 0; i < 8; i++) c[i] = col[s + i];
    }
    for (int j = s; j < e; j += 8) {
        int cn[8];
        if (j + 8 < e) {
            #pragma unroll
            for (int i = 0; i < 8; i++) cn[i] = col[j + 8 + i];
        } else {
            #pragma unroll
            for (int i = 0; i < 8; i++) cn[i] = 0;
        }
        float w[8];
        f16x2 v[8];
        #pragma unroll
        for (int i = 0; i < 8; i++) w[i] = dinv[c[i]];
        #pragma unroll
        for (int i = 0; i < 8; i++) v[i] = hp[(unsigned)(c[i] * 64 + lane)];
        #pragma unroll
        for (int i = 0; i < 8; i++) {
            ax[i] = fmaf((float)v[i][0], w[i], ax[i]);
            ay[i] = fmaf((float)v[i][1], w[i], ay[i]);
        }
        #pragma unroll
        for (int i = 0; i < 8; i++) c[i] = cn[i];
    }
    float sx = ((ax[0] + ax[1]) + (ax[2] + ax[3])) + ((ax[4] + ax[5]) + (ax[6] + ax[7]));
    float sy = ((ay[0] + ay[1]) + (ay[2] + ay[3])) + ((ay[4] + ay[5]) + (ay[6] + ay[7]));
    sx = fmaf((float)sv[0], di, sx);
    sy = fmaf((float)sv[1], di, sy);
    float2 bv = ((const float2*)bias)[lane];
    float ox = fmaxf(sx * di + bv.x, 0.f);
    float oy = fmaxf(sy * di + bv.y, 0.f);
    f16x2 o;
    o[0] = (f16)ox; o[1] = (f16)oy;
    ((f16x2*)(out + (size_t)node * 128))[lane] = o;
}

// ---------- aggregation D=64: 8-wide batches, col prefetch. 32 lanes/node. ----------
__global__ __launch_bounds__(256) void agg64(const f16* __restrict__ h,
                                             const int2* __restrict__ rsp,
                                             const int* __restrict__ col,
                                             const float* __restrict__ dinv,
                                             const float* __restrict__ bias,
                                             float* __restrict__ out) {
    int node = (blockIdx.x * 256 + threadIdx.x) >> 5;
    int lane = threadIdx.x & 31;
    if (node >= NN) return;
    float di = dinv[node];
    const f16x2* hp = (const f16x2*)h;
    f16x2 sv = hp[(unsigned)(node * 32 + lane)];
    int2 g = rsp[node];
    int s = g.x, e = g.x + g.y;
    float ax[8], ay[8];
    #pragma unroll
    for (int i = 0; i < 8; i++) { ax[i] = 0.f; ay[i] = 0.f; }
    int c[8];
    if (s < e) {
        #pragma unroll
        for (int i = 0; i < 8; i++) c[i] = col[s + i];
    }
    for (int j = s; j < e; j += 8) {
        int cn[8];
        if (j + 8 < e) {
            #pragma unroll
            for (int i = 0; i < 8; i++) cn[i] = col[j + 8 + i];
        } else {
            #pragma unroll
            for (int i = 0; i < 8; i++) cn[i] = 0;
        }
        float w[8];
        f16x2 v[8];
        #pragma unroll
        for (int i = 0; i < 8; i++) w[i] = dinv[c[i]];
        #pragma unroll
        for (int i = 0; i < 8; i++) v[i] = hp[(unsigned)(c[i] * 32 + lane)];
        #pragma unroll
        for (int i = 0; i < 8; i++) {
            ax[i] = fmaf((float)v[i][0], w[i], ax[i]);
            ay[i] = fmaf((float)v[i][1], w[i], ay[i]);
        }
        #pragma unroll
        for (int i = 0; i < 8; i++) c[i] = cn[i];
    }
    float sx = ((ax[0] + ax[1]) + (ax[2] + ax[3])) + ((ax[4] + ax[5]) + (ax[6] + ax[7]));
    float sy = ((ay[0] + ay[1]) + (ay[2] + ay[3])) + ((ay[4] + ay[5]) + (ay[6] + ay[7]));
    sx = fmaf((float)sv[0], di, sx);
    sy = fmaf((float)sv[1], di, sy);
    float2 bv = ((const float2*)bias)[lane];
    float2 o = make_float2(sx * di + bv.x, sy * di + bv.y);
    ((float2*)(out + (size_t)node * 64))[lane] = o;
}

extern "C" void kernel_launch(void* const* d_in, const int* in_sizes, int n_in,
                              void* d_out, int out_size, void* d_ws, size_t ws_size,
                              hipStream_t stream) {
    const float* x  = (const float*)d_in[0];
    const void*  ei = d_in[1];
    const float* W1 = (const float*)d_in[2];
    const float* b1 = (const float*)d_in[3];
    const float* W2 = (const float*)d_in[4];
    const float* b2 = (const float*)d_in[5];
    float* out = (float*)d_out;

    char* wsp = (char*)d_ws;
    size_t off = 0;
    auto alloc = [&](size_t bytes) {
        void* p = wsp + off;
        off += (bytes + 255) & ~(size_t)255;
        return p;
    };
    f16*      h1     = (f16*)alloc((size_t)(NN + 1) * 128 * 2);  // +1 sentinel row
    f16*      a1     = (f16*)alloc((size_t)NN * 128 * 2);        // also aliased as col32
    f16*      h2     = (f16*)alloc((size_t)(NN + 1) * 64 * 2);   // +1 sentinel row
    int*      col    = (int*)alloc((size_t)NB * PCAP * 4);       // padded CSR
    int2*     rsp    = (int2*)alloc((size_t)NN * 8);             // (start, padded_deg)
    float*    dinv   = (float*)alloc((size_t)(NN + 1) * 4);
    int*      cursor = (int*)alloc((size_t)NB * 4);
    f16*      W1h    = (f16*)alloc(128 * 128 * 2);
    f16*      W1l    = (f16*)alloc(128 * 128 * 2);
    f16*      W2h    = (f16*)alloc(64 * 128 * 2);
    f16*      W2l    = (f16*)alloc(64 * 128 * 2);
    unsigned* col32  = (unsigned*)a1;  // alias: consumed before a1 is written
    (void)ws_size; (void)in_sizes; (void)n_in; (void)out_size;

    // zero sentinel rows (gathered by pad entries with weight 0; must be finite)
    hipMemsetAsync(h1 + (size_t)NN * 128, 0, 256, stream);
    hipMemsetAsync(h2 + (size_t)NN * 64, 0, 128, stream);

    prep_split<<<96, 256, 0, stream>>>(W1, W2, W1h, W1l, W2h, W2l);
    init_buckets<<<2, 256, 0, stream>>>(cursor);
    partition_kernel<<<PBLK, 256, 0, stream>>>(ei, cursor, col32);
    bucket_fill_kernel<<<NB, 256, 0, stream>>>(col32, cursor, rsp, dinv, col);

    gemm_mfma<128, 1><<<(NN + 63) / 64, 256, 0, stream>>>(x, W1h, W1l, h1);
    agg128<<<(NN * 64) / 256, 256, 0, stream>>>(h1, rsp, col, dinv, b1, a1);
    gemm_mfma<64, 0><<<(NN + 63) / 64, 256, 0, stream>>>(a1, W2h, W2l, h2);
    agg64<<<(NN * 32) / 256, 256, 0, stream>>>(h2, rsp, col, dinv, b2, out);
}